// Round 1
// baseline (3575.955 us; speedup 1.0000x reference)
//
#include <hip/hip_runtime.h>

#define T 4096
#define Hdim 2048
#define Idim 2816
#define TWO_I 5632
#define E 16
#define Ktop 8

#define BM 128
#define BK 32
#define LDA 40  // padded LDS stride (bf16 elems): 80 B rows -> 16B-aligned frags, <=2-way banks

typedef __attribute__((ext_vector_type(8))) short short8;
typedef __attribute__((ext_vector_type(4))) float floatx4;

__device__ inline unsigned short f2bf(float f) {
  union { float f; unsigned u; } v; v.f = f;
  unsigned r = v.u + 0x7FFFu + ((v.u >> 16) & 1u);
  return (unsigned short)(r >> 16);
}

// ---------------- routing ----------------
__global__ void k_route(const int* __restrict__ idx, const float* __restrict__ wts,
                        int* __restrict__ counts, int* __restrict__ tok,
                        float* __restrict__ wl) {
  int t = blockIdx.x * blockDim.x + threadIdx.x;
  if (t >= T) return;
  float w[E];
#pragma unroll
  for (int e = 0; e < E; ++e) w[e] = 0.f;
  unsigned mask = 0;
#pragma unroll
  for (int j = 0; j < Ktop; ++j) {
    int e = idx[t * Ktop + j];
    w[e] += wts[t * Ktop + j];
    mask |= (1u << e);
  }
#pragma unroll
  for (int e = 0; e < E; ++e) {
    if (mask & (1u << e)) {
      int slot = atomicAdd(&counts[e], 1);
      tok[e * T + slot] = t;
      wl[e * T + slot] = w[e];
    }
  }
}

__global__ void k_prefix(const int* __restrict__ counts, int* __restrict__ offsets) {
  if (threadIdx.x == 0 && blockIdx.x == 0) {
    int s = 0;
    for (int e = 0; e < E; ++e) { offsets[e] = s; s += counts[e]; }
    offsets[E] = s;
  }
}

// ---------------- x -> bf16 ----------------
__global__ void k_cast(const float* __restrict__ x, unsigned short* __restrict__ xb, int n4) {
  int i = blockIdx.x * blockDim.x + threadIdx.x;
  int stride = gridDim.x * blockDim.x;
  const float4* xv = (const float4*)x;
  for (; i < n4; i += stride) {
    float4 v = xv[i];
    ushort4 o;
    o.x = f2bf(v.x); o.y = f2bf(v.y); o.z = f2bf(v.z); o.w = f2bf(v.w);
    ((ushort4*)xb)[i] = o;
  }
}

// ---------------- GEMM1: gathered x @ Wgu, fused SiLU*up -> act (bf16) ----------------
// grid: (I/64, T/BM, E), block 256 (4 waves). Each block: 128 tokens x 64 cols of g AND u.
__global__ __launch_bounds__(256, 2) void k_gemm1(
    const unsigned short* __restrict__ xb, const float* __restrict__ gup,
    const int* __restrict__ counts, const int* __restrict__ offsets,
    const int* __restrict__ tok, unsigned short* __restrict__ act) {
  const int e = blockIdx.z;
  const int cnt = counts[e];
  const int m0 = blockIdx.y * BM;
  if (m0 >= cnt) return;
  const int rows = min(BM, cnt - m0);
  const int n0 = blockIdx.x * 64;
  const int aoff = offsets[e];
  const int tid = threadIdx.x;

  __shared__ unsigned short As[BM * LDA];
  __shared__ unsigned short Bg[64 * LDA];
  __shared__ unsigned short Bu[64 * LDA];

  // A staging: 2 threads/row, 16 bf16 each
  const int arow = tid >> 1;
  const int acol0 = (tid & 1) * 16;
  const int tkn = (arow < rows) ? tok[e * T + m0 + arow] : -1;
  const unsigned short* asrc = (tkn >= 0) ? (xb + (size_t)tkn * Hdim + acol0) : (const unsigned short*)0;

  // B staging: 8 threads/row of 64 cols, 8 floats each
  const int bk = tid >> 3;            // 0..31
  const int bn0 = (tid & 7) * 8;      // 0..56
  const float* gbase = gup + (size_t)e * Hdim * TWO_I + (size_t)bk * TWO_I + (size_t)(n0 + bn0);

  const int lane = tid & 63;
  const int wv = tid >> 6;
  const int wm = wv * 32;   // wave's 32-row strip
  const int lm = lane & 15;
  const int lq = lane >> 4;

  floatx4 zero4 = {0.f, 0.f, 0.f, 0.f};
  floatx4 accg[2][4], accu[2][4];
#pragma unroll
  for (int i = 0; i < 2; ++i)
#pragma unroll
    for (int j = 0; j < 4; ++j) { accg[i][j] = zero4; accu[i][j] = zero4; }

  for (int k0 = 0; k0 < Hdim; k0 += BK) {
    __syncthreads();
    // ---- stage A (gathered token rows, bf16 direct copy) ----
    uint4 a0v = {0, 0, 0, 0}, a1v = {0, 0, 0, 0};
    if (tkn >= 0) {
      const uint4* s = (const uint4*)(asrc + k0);
      a0v = s[0]; a1v = s[1];
    }
    *(uint4*)&As[arow * LDA + acol0] = a0v;
    *(uint4*)&As[arow * LDA + acol0 + 8] = a1v;
    // ---- stage B (fp32 -> bf16, transposed to [n][k]) ----
    const float* gs = gbase + (size_t)k0 * TWO_I;
    float4 g0 = *(const float4*)(gs);
    float4 g1 = *(const float4*)(gs + 4);
    float4 u0 = *(const float4*)(gs + Idim);
    float4 u1 = *(const float4*)(gs + Idim + 4);
    unsigned short* wg = &Bg[bk];
    unsigned short* wu = &Bu[bk];
    wg[(bn0 + 0) * LDA] = f2bf(g0.x); wg[(bn0 + 1) * LDA] = f2bf(g0.y);
    wg[(bn0 + 2) * LDA] = f2bf(g0.z); wg[(bn0 + 3) * LDA] = f2bf(g0.w);
    wg[(bn0 + 4) * LDA] = f2bf(g1.x); wg[(bn0 + 5) * LDA] = f2bf(g1.y);
    wg[(bn0 + 6) * LDA] = f2bf(g1.z); wg[(bn0 + 7) * LDA] = f2bf(g1.w);
    wu[(bn0 + 0) * LDA] = f2bf(u0.x); wu[(bn0 + 1) * LDA] = f2bf(u0.y);
    wu[(bn0 + 2) * LDA] = f2bf(u0.z); wu[(bn0 + 3) * LDA] = f2bf(u0.w);
    wu[(bn0 + 4) * LDA] = f2bf(u1.x); wu[(bn0 + 5) * LDA] = f2bf(u1.y);
    wu[(bn0 + 6) * LDA] = f2bf(u1.z); wu[(bn0 + 7) * LDA] = f2bf(u1.w);
    __syncthreads();
    // ---- MFMA ----
    short8 af0 = *(const short8*)&As[(wm + lm) * LDA + lq * 8];
    short8 af1 = *(const short8*)&As[(wm + 16 + lm) * LDA + lq * 8];
#pragma unroll
    for (int j = 0; j < 4; ++j) {
      short8 bgf = *(const short8*)&Bg[(j * 16 + lm) * LDA + lq * 8];
      short8 buf2 = *(const short8*)&Bu[(j * 16 + lm) * LDA + lq * 8];
      accg[0][j] = __builtin_amdgcn_mfma_f32_16x16x32_bf16(af0, bgf, accg[0][j], 0, 0, 0);
      accg[1][j] = __builtin_amdgcn_mfma_f32_16x16x32_bf16(af1, bgf, accg[1][j], 0, 0, 0);
      accu[0][j] = __builtin_amdgcn_mfma_f32_16x16x32_bf16(af0, buf2, accu[0][j], 0, 0, 0);
      accu[1][j] = __builtin_amdgcn_mfma_f32_16x16x32_bf16(af1, buf2, accu[1][j], 0, 0, 0);
    }
  }

  // ---- epilogue: act = silu(g)*u -> bf16 ----
#pragma unroll
  for (int i = 0; i < 2; ++i) {
#pragma unroll
    for (int r = 0; r < 4; ++r) {
      int row = wm + i * 16 + lq * 4 + r;
      if (row < rows) {
        size_t ar = (size_t)(aoff + m0 + row) * Idim;
#pragma unroll
        for (int j = 0; j < 4; ++j) {
          float g = accg[i][j][r];
          float u = accu[i][j][r];
          float a = g / (1.f + __expf(-g)) * u;
          act[ar + (size_t)(n0 + j * 16 + lm)] = f2bf(a);
        }
      }
    }
  }
}

// ---------------- GEMM2: act @ Wd, scaled scatter-add into out ----------------
// grid: (H/128, T/BM, E), block 256 (4 waves). Each block: 128 act rows x 128 out cols.
__global__ __launch_bounds__(256, 2) void k_gemm2(
    const unsigned short* __restrict__ act, const float* __restrict__ wd,
    const int* __restrict__ counts, const int* __restrict__ offsets,
    const int* __restrict__ tok, const float* __restrict__ wl,
    float* __restrict__ out) {
  const int e = blockIdx.z;
  const int cnt = counts[e];
  const int m0 = blockIdx.y * BM;
  if (m0 >= cnt) return;
  const int rows = min(BM, cnt - m0);
  const int n0 = blockIdx.x * 128;
  const int aoff = offsets[e];
  const int tid = threadIdx.x;

  __shared__ unsigned short As[BM * LDA];
  __shared__ unsigned short Bs[128 * LDA];

  const int arow = tid >> 1;
  const int acol0 = (tid & 1) * 16;
  const unsigned short* asrc = act + (size_t)(aoff + m0 + arow) * Idim + acol0;

  const int bk = tid >> 3;             // 0..31
  const int bn0 = (tid & 7) * 16;      // 0..112
  const float* bbase = wd + (size_t)e * Idim * Hdim + (size_t)bk * Hdim + (size_t)(n0 + bn0);

  const int lane = tid & 63;
  const int wv = tid >> 6;
  const int wm = wv * 32;
  const int lm = lane & 15;
  const int lq = lane >> 4;

  floatx4 zero4 = {0.f, 0.f, 0.f, 0.f};
  floatx4 acc[2][8];
#pragma unroll
  for (int i = 0; i < 2; ++i)
#pragma unroll
    for (int j = 0; j < 8; ++j) acc[i][j] = zero4;

  for (int k0 = 0; k0 < Idim; k0 += BK) {
    __syncthreads();
    const uint4* s = (const uint4*)(asrc + k0);
    uint4 a0v = s[0];
    uint4 a1v = s[1];
    *(uint4*)&As[arow * LDA + acol0] = a0v;
    *(uint4*)&As[arow * LDA + acol0 + 8] = a1v;
    const float* bs = bbase + (size_t)k0 * Hdim;
    float4 b0 = ((const float4*)bs)[0];
    float4 b1 = ((const float4*)bs)[1];
    float4 b2 = ((const float4*)bs)[2];
    float4 b3 = ((const float4*)bs)[3];
    unsigned short* bw = &Bs[bk];
    bw[(bn0 + 0) * LDA] = f2bf(b0.x);  bw[(bn0 + 1) * LDA] = f2bf(b0.y);
    bw[(bn0 + 2) * LDA] = f2bf(b0.z);  bw[(bn0 + 3) * LDA] = f2bf(b0.w);
    bw[(bn0 + 4) * LDA] = f2bf(b1.x);  bw[(bn0 + 5) * LDA] = f2bf(b1.y);
    bw[(bn0 + 6) * LDA] = f2bf(b1.z);  bw[(bn0 + 7) * LDA] = f2bf(b1.w);
    bw[(bn0 + 8) * LDA] = f2bf(b2.x);  bw[(bn0 + 9) * LDA] = f2bf(b2.y);
    bw[(bn0 + 10) * LDA] = f2bf(b2.z); bw[(bn0 + 11) * LDA] = f2bf(b2.w);
    bw[(bn0 + 12) * LDA] = f2bf(b3.x); bw[(bn0 + 13) * LDA] = f2bf(b3.y);
    bw[(bn0 + 14) * LDA] = f2bf(b3.z); bw[(bn0 + 15) * LDA] = f2bf(b3.w);
    __syncthreads();
    short8 af0 = *(const short8*)&As[(wm + lm) * LDA + lq * 8];
    short8 af1 = *(const short8*)&As[(wm + 16 + lm) * LDA + lq * 8];
#pragma unroll
    for (int j = 0; j < 8; ++j) {
      short8 bf2 = *(const short8*)&Bs[(j * 16 + lm) * LDA + lq * 8];
      acc[0][j] = __builtin_amdgcn_mfma_f32_16x16x32_bf16(af0, bf2, acc[0][j], 0, 0, 0);
      acc[1][j] = __builtin_amdgcn_mfma_f32_16x16x32_bf16(af1, bf2, acc[1][j], 0, 0, 0);
    }
  }

#pragma unroll
  for (int i = 0; i < 2; ++i) {
#pragma unroll
    for (int r = 0; r < 4; ++r) {
      int row = wm + i * 16 + lq * 4 + r;
      if (row < rows) {
        int t = tok[e * T + m0 + row];
        float w = wl[e * T + m0 + row];
        float* orow = out + (size_t)t * Hdim + n0;
#pragma unroll
        for (int j = 0; j < 8; ++j) {
          atomicAdd(&orow[j * 16 + lm], w * acc[i][j][r]);
        }
      }
    }
  }
}

// ---------------- launch ----------------
extern "C" void kernel_launch(void* const* d_in, const int* in_sizes, int n_in,
                              void* d_out, int out_size, void* d_ws, size_t ws_size,
                              hipStream_t stream) {
  const float* x   = (const float*)d_in[0];
  const float* gup = (const float*)d_in[1];
  const float* wdp = (const float*)d_in[2];
  const int* idx   = (const int*)d_in[3];
  const float* wts = (const float*)d_in[4];
  float* out = (float*)d_out;

  // workspace layout (all 256B-aligned)
  char* wsb = (char*)d_ws;
  int* counts  = (int*)(wsb);                          // 16 ints
  int* offsets = (int*)(wsb + 256);                    // 17 ints
  int* tok     = (int*)(wsb + 512);                    // E*T ints = 256 KiB
  float* wl    = (float*)(wsb + 512 + 262144);         // E*T floats = 256 KiB
  unsigned short* xb  = (unsigned short*)(wsb + 512 + 524288);              // T*H bf16 = 16 MiB
  unsigned short* act = (unsigned short*)(wsb + 512 + 524288 + 16777216);   // (T*8+128) x I bf16

  hipMemsetAsync(d_out, 0, (size_t)out_size * sizeof(float), stream);
  hipMemsetAsync(counts, 0, 256, stream);

  k_route<<<dim3(T / 256), dim3(256), 0, stream>>>(idx, wts, counts, tok, wl);
  k_prefix<<<dim3(1), dim3(64), 0, stream>>>(counts, offsets);
  k_cast<<<dim3(2048), dim3(256), 0, stream>>>(x, xb, T * Hdim / 4);
  k_gemm1<<<dim3(Idim / 64, T / BM, E), dim3(256), 0, stream>>>(xb, gup, counts, offsets, tok, act);
  k_gemm2<<<dim3(Hdim / 128, T / BM, E), dim3(256), 0, stream>>>(act, wdp, counts, offsets, tok, wl, out);
}